// Round 9
// baseline (343.550 us; speedup 1.0000x reference)
//
#include <hip/hip_runtime.h>

#define N_NODES 50000
#define HIDDEN  64
#define N_EDGES 1200000

#define BSHIFT 7                       // 128 nodes per bucket
#define BUKSZ  128
#define NBUK   391                     // ceil(50000/128)
#define ABLK   512                     // block-local-sort blocks
#define CH     2344                    // ceil(N_EDGES/ABLK)
#define PAD2   4096                    // csr capacity per bucket (avg 3072 + 4-align pad)
#define FWAVES 12500                   // fused-layer waves (1 node per wave-iteration)
#define FBLK   (FWAVES / 4)            // 3125 blocks
#define NPW    4                       // nodes per wave (strided)

typedef unsigned short ushort_t;

__device__ __forceinline__ float bcastf(float v, int k) {
    return __int_as_float(__builtin_amdgcn_readlane(__float_as_int(v), k));
}
__device__ __forceinline__ unsigned f2bf(float x) {    // f32 -> bf16 RNE
    unsigned u = __float_as_uint(x);
    u += 0x7fffu + ((u >> 16) & 1u);
    return u >> 16;
}
__device__ __forceinline__ float bfl(unsigned w) { return __uint_as_float(w << 16); }
__device__ __forceinline__ float bfh(unsigned w) { return __uint_as_float(w & 0xffff0000u); }
__device__ __forceinline__ void bfly(float4& a) {      // all lanes end with group-sum
    a.x += __shfl_xor(a.x, 16); a.y += __shfl_xor(a.y, 16);
    a.z += __shfl_xor(a.z, 16); a.w += __shfl_xor(a.w, 16);
    a.x += __shfl_xor(a.x, 32); a.y += __shfl_xor(a.y, 32);
    a.z += __shfl_xor(a.z, 32); a.w += __shfl_xor(a.w, 32);
}

// ---------------- Kernel A: block-local bucket sort (pure stores) + W packing ----------------
__global__ __launch_bounds__(512) void build_a_kernel(const int* __restrict__ ei,
                                                      int* __restrict__ tmp,
                                                      int* __restrict__ starts_m,
                                                      int* __restrict__ counts_m,
                                                      const float* __restrict__ Wn2, const float* __restrict__ Ws2,
                                                      const float* __restrict__ Wn3, const float* __restrict__ Ws3,
                                                      const float* __restrict__ Wn4, const float* __restrict__ Ws4,
                                                      uint4* __restrict__ pw) {
    __shared__ int hist[NBUK];
    __shared__ int cur[NBUK];
    __shared__ int stage[CH];
    int b = blockIdx.x, tid = threadIdx.x;
    if (b < ABLK) {
        int base = b * CH;
        int cnt = N_EDGES - base; if (cnt > CH) cnt = CH;
        for (int i = tid; i < NBUK; i += 512) hist[i] = 0;
        __syncthreads();
        for (int i = tid; i < cnt; i += 512)
            atomicAdd(&hist[ei[N_EDGES + base + i] >> BSHIFT], 1);
        __syncthreads();
        int v = (tid < NBUK) ? hist[tid] : 0;
#pragma unroll
        for (int o = 1; o < NBUK; o <<= 1) {
            __syncthreads();
            int y = (tid >= o && tid < NBUK) ? hist[tid - o] : 0;
            __syncthreads();
            if (tid < NBUK) hist[tid] += y;
        }
        __syncthreads();
        if (tid < NBUK) {
            int excl = hist[tid] - v;
            cur[tid] = excl;
            starts_m[tid * ABLK + b] = base + excl;
            counts_m[tid * ABLK + b] = v;
        }
        __syncthreads();
        for (int i = tid; i < cnt; i += 512) {
            int src = ei[base + i];
            int dst = ei[N_EDGES + base + i];
            int p = atomicAdd(&cur[dst >> BSHIFT], 1);
            stage[p] = src | ((dst & (BUKSZ - 1)) << 16);
        }
        __syncthreads();
        for (int i = tid; i < cnt; i += 512) tmp[base + i] = stage[i];
    } else {
        // pack W_nbr|W_self (layers 2..4) bf16-interleaved: pw[layer*1024 + k*16 + q]
        int layer = b - ABLK;
        const float* Wn = (layer == 0) ? Wn2 : (layer == 1) ? Wn3 : Wn4;
        const float* Ws = (layer == 0) ? Ws2 : (layer == 1) ? Ws3 : Ws4;
        for (int e = tid; e < 1024; e += 512) {
            const float4 a = *(const float4*)(Wn + e * 4);
            const float4 c = *(const float4*)(Ws + e * 4);
            uint4 o;
            o.x = f2bf(a.x) | (f2bf(a.y) << 16);
            o.y = f2bf(a.z) | (f2bf(a.w) << 16);
            o.z = f2bf(c.x) | (f2bf(c.y) << 16);
            o.w = f2bf(c.z) | (f2bf(c.w) << 16);
            pw[layer * 1024 + e] = o;
        }
    }
}

// ---------------- Kernel B: per-bucket counting sort (4-aligned) + gemm1 ----------------
__global__ __launch_bounds__(512) void build_b_kernel(const int* __restrict__ tmp,
                                                      const int* __restrict__ starts_m,
                                                      const int* __restrict__ counts_m,
                                                      int2* __restrict__ row_info,
                                                      ushort_t* __restrict__ csr,
                                                      const float* __restrict__ x,
                                                      const float* __restrict__ Wrel,
                                                      const float* __restrict__ Wroot,
                                                      const float* __restrict__ bias,
                                                      ushort_t* __restrict__ tbf,
                                                      float* __restrict__ u) {
    __shared__ int sl[ABLK];
    __shared__ int cl[ABLK];
    __shared__ int hist[BUKSZ];
    __shared__ int cur[BUKSZ];
    __shared__ ushort_t stage[PAD2];
    int b = blockIdx.x, tid = threadIdx.x;
    if (b < NBUK) {
        sl[tid] = starts_m[b * ABLK + tid];
        cl[tid] = counts_m[b * ABLK + tid];
        if (tid < BUKSZ) hist[tid] = 0;
        __syncthreads();
        {   // thread-per-segment histogram
            int s = sl[tid], c = cl[tid];
            for (int i = 0; i < c; ++i) atomicAdd(&hist[tmp[s + i] >> 16], 1);
        }
        __syncthreads();
        int v = (tid < BUKSZ) ? hist[tid] : 0;
        int vr = (v + 3) & ~3;                 // 4-aligned per-node segment
        __syncthreads();
        if (tid < BUKSZ) hist[tid] = vr;
#pragma unroll
        for (int o = 1; o < BUKSZ; o <<= 1) {
            __syncthreads();
            int y = (tid >= o && tid < BUKSZ) ? hist[tid - o] : 0;
            __syncthreads();
            if (tid < BUKSZ) hist[tid] += y;
        }
        __syncthreads();
        if (tid < BUKSZ) {
            int excl = hist[tid] - vr;
            cur[tid] = excl;
            int node = (b << BSHIFT) + tid;
            if (node < N_NODES) row_info[node] = make_int2(b * PAD2 + excl, v);
        }
        __syncthreads();
        {   // thread-per-segment placement
            int s = sl[tid], c = cl[tid];
            for (int i = 0; i < c; ++i) {
                int p = tmp[s + i];
                int slot = atomicAdd(&cur[p >> 16], 1);
                stage[slot] = (ushort_t)(p & 0xFFFF);
            }
        }
        __syncthreads();
        int total = hist[BUKSZ - 1];           // rounded; pad slots garbage (clamped on use)
        for (int i = tid; i < total; i += 512) csr[b * PAD2 + i] = stage[i];
    } else {
        // gemm1: t1 = x@Wrel (bf16), u1 = x@Wroot + b1
        int lane = tid & 63;
        float wn[64], ws[64];
#pragma unroll
        for (int k = 0; k < 64; ++k) {
            wn[k] = Wrel[k * 64 + lane];
            ws[k] = Wroot[k * 64 + lane];
        }
        float bv = bias[lane];
        int wave = (b - NBUK) * 8 + (tid >> 6);
        int nwaves = (gridDim.x - NBUK) * 8;
        if (wave == 0) tbf[(size_t)N_NODES * 64 + lane] = 0;   // zero clamp row
        for (int i = wave; i < N_NODES; i += nwaves) {
            float hv = x[i * 64 + lane];
            float tacc = 0.f, uacc = bv;
#pragma unroll
            for (int k = 0; k < 64; ++k) {
                float hk = bcastf(hv, k);
                tacc = fmaf(hk, wn[k], tacc);
                uacc = fmaf(hk, ws[k], uacc);
            }
            tbf[(size_t)i * 64 + lane] = (ushort_t)f2bf(tacc);
            u[(size_t)i * 64 + lane] = uacc;
        }
    }
}

// ---------------- shfl-free gather-aggregate for one node (R8-proven) ----------------
__device__ __forceinline__ float4 agg_core(const ushort_t* __restrict__ tbf,
                                           const ushort_t* __restrict__ csr,
                                           int start, int deg, int g, int q) {
    const ushort_t* cp = csr + start;          // start is 4-aligned
    float4 a0{0,0,0,0}, a1{0,0,0,0}, a2{0,0,0,0}, a3{0,0,0,0};
    for (int base = 0; base < deg; base += 16) {
        int m = base + 4 * g;
        const uint2 iv = *(const uint2*)(cp + m);
        int s0 = (m + 0 < deg) ? (int)(iv.x & 0xFFFF) : N_NODES;
        int s1 = (m + 1 < deg) ? (int)(iv.x >> 16)    : N_NODES;
        int s2 = (m + 2 < deg) ? (int)(iv.y & 0xFFFF) : N_NODES;
        int s3 = (m + 3 < deg) ? (int)(iv.y >> 16)    : N_NODES;
        const uint2 w0 = *(const uint2*)(tbf + (size_t)s0 * 64 + q * 4);
        const uint2 w1 = *(const uint2*)(tbf + (size_t)s1 * 64 + q * 4);
        const uint2 w2 = *(const uint2*)(tbf + (size_t)s2 * 64 + q * 4);
        const uint2 w3 = *(const uint2*)(tbf + (size_t)s3 * 64 + q * 4);
        a0.x += bfl(w0.x); a0.y += bfh(w0.x); a0.z += bfl(w0.y); a0.w += bfh(w0.y);
        a1.x += bfl(w1.x); a1.y += bfh(w1.x); a1.z += bfl(w1.y); a1.w += bfh(w1.y);
        a2.x += bfl(w2.x); a2.y += bfh(w2.x); a2.z += bfl(w2.y); a2.w += bfh(w2.y);
        a3.x += bfl(w3.x); a3.y += bfh(w3.x); a3.z += bfl(w3.y); a3.w += bfh(w3.y);
    }
    float4 acc;
    acc.x = (a0.x + a1.x) + (a2.x + a3.x);
    acc.y = (a0.y + a1.y) + (a2.y + a3.y);
    acc.z = (a0.z + a1.z) + (a2.z + a3.z);
    acc.w = (a0.w + a1.w) + (a2.w + a3.w);
    bfly(acc);
    return acc;
}

// ---------------- fused: agg(layer k) [+ dout] + gemm(layer k+1) ----------------
__global__ __launch_bounds__(256, 6) void fused_kernel(const ushort_t* __restrict__ tin,
                                                       const float* __restrict__ uin,
                                                       const int2* __restrict__ row_info,
                                                       const ushort_t* __restrict__ csr,
                                                       const uint4* __restrict__ pwL,
                                                       const float* __restrict__ bias_next,
                                                       ushort_t* __restrict__ tout,
                                                       float* __restrict__ uout,
                                                       float* __restrict__ dout,
                                                       int use_mean) {
    __shared__ uint4 wlds[1024];   // packed W_nbr|W_self bf16, 16 KB
    __shared__ float blds[64];
    int tid = threadIdx.x;
    for (int i = tid; i < 1024; i += 256) wlds[i] = pwL[i];
    if (tid < 64) blds[tid] = bias_next[tid];
    if (blockIdx.x == 0 && tid < 32)       // zero clamp row of tout (32 uints = 64 ushorts... x2)
        ((unsigned*)(tout + (size_t)N_NODES * 64))[tid] = 0;
    __syncthreads();
    int lane = tid & 63, g = lane >> 4, q = lane & 15;
    int w = blockIdx.x * 4 + (tid >> 6);

#pragma unroll
    for (int i = 0; i < NPW; ++i) {
        int node = w + FWAVES * i;
        if (node >= N_NODES) continue;
        int2 ri = row_info[node];
        float4 acc = agg_core(tin, csr, ri.x, ri.y, g, q);
        float sc = use_mean ? 1.f / fmaxf((float)ri.y, 1.f) : 1.f;
        const float4 uv = *(const float4*)(uin + (size_t)node * 64 + q * 4);
        float4 h;
        h.x = fmaxf(uv.x + acc.x * sc, 0.f);
        h.y = fmaxf(uv.y + acc.y * sc, 0.f);
        h.z = fmaxf(uv.z + acc.z * sc, 0.f);
        h.w = fmaxf(uv.w + acc.w * sc, 0.f);
        if (dout && g == 0)
            *(float4*)(dout + (size_t)node * 64 + q * 4) = h;
        // gemm: group g covers k in [16g,16g+16); h_k lives in lane (k>>2) of group 0
        float4 tp{0,0,0,0}, up{0,0,0,0};
#pragma unroll
        for (int j = 0; j < 16; ++j) {
            uint4 wv = wlds[(16 * g + j) * 16 + q];
            int srcl = 4 * g + (j >> 2);
            float hk;
            if ((j & 3) == 0)      hk = __shfl(h.x, srcl);
            else if ((j & 3) == 1) hk = __shfl(h.y, srcl);
            else if ((j & 3) == 2) hk = __shfl(h.z, srcl);
            else                   hk = __shfl(h.w, srcl);
            tp.x = fmaf(hk, bfl(wv.x), tp.x); tp.y = fmaf(hk, bfh(wv.x), tp.y);
            tp.z = fmaf(hk, bfl(wv.y), tp.z); tp.w = fmaf(hk, bfh(wv.y), tp.w);
            up.x = fmaf(hk, bfl(wv.z), up.x); up.y = fmaf(hk, bfh(wv.z), up.y);
            up.z = fmaf(hk, bfl(wv.w), up.z); up.w = fmaf(hk, bfh(wv.w), up.w);
        }
        bfly(tp); bfly(up);
        if (g == 0) {
            const float4 bv = *(const float4*)&blds[q * 4];
            float4 uo;
            uo.x = up.x + bv.x; uo.y = up.y + bv.y;
            uo.z = up.z + bv.z; uo.w = up.w + bv.w;
            *(float4*)(uout + (size_t)node * 64 + q * 4) = uo;
            uint2 tpk;
            tpk.x = f2bf(tp.x) | (f2bf(tp.y) << 16);
            tpk.y = f2bf(tp.z) | (f2bf(tp.w) << 16);
            *(uint2*)(tout + (size_t)node * 64 + q * 4) = tpk;
        }
    }
}

// ---------------- final agg-only (R8-proven) ----------------
__global__ __launch_bounds__(256, 8) void agg_kernel(const ushort_t* __restrict__ tbf,
                                                     const float* __restrict__ u,
                                                     const int2* __restrict__ row_info,
                                                     const ushort_t* __restrict__ csr,
                                                     float* __restrict__ out, int use_mean) {
    int lane = threadIdx.x & 63;
    int g = lane >> 4, q = lane & 15;
    int node = (blockIdx.x * 256 + threadIdx.x) >> 6;
    if (node >= N_NODES) return;
    int2 ri = row_info[node];
    float4 acc = agg_core(tbf, csr, ri.x, ri.y, g, q);
    float scale = use_mean ? 1.f / fmaxf((float)ri.y, 1.f) : 1.f;
    if (g == 0) {
        const float4 uv = *(const float4*)(u + (size_t)node * 64 + q * 4);
        float4 r;
        r.x = fmaxf(uv.x + acc.x * scale, 0.f);
        r.y = fmaxf(uv.y + acc.y * scale, 0.f);
        r.z = fmaxf(uv.z + acc.z * scale, 0.f);
        r.w = fmaxf(uv.w + acc.w * scale, 0.f);
        *(float4*)(out + (size_t)node * 64 + q * 4) = r;
    }
}

// ---------------- launch: 6 dispatches ----------------
extern "C" void kernel_launch(void* const* d_in, const int* in_sizes, int n_in,
                              void* d_out, int out_size, void* d_ws, size_t ws_size,
                              hipStream_t stream) {
    const float* x      = (const float*)d_in[0];
    const int*   ei     = (const int*)d_in[1];
    const float* Wrel1  = (const float*)d_in[2];
    const float* Wroot1 = (const float*)d_in[3];
    const float* b1     = (const float*)d_in[4];
    const float* Wself2 = (const float*)d_in[5];
    const float* Wnbr2  = (const float*)d_in[6];
    const float* b2     = (const float*)d_in[7];
    const float* Wself3 = (const float*)d_in[8];
    const float* Wnbr3  = (const float*)d_in[9];
    const float* b3     = (const float*)d_in[10];
    const float* Wself4 = (const float*)d_in[11];
    const float* Wnbr4  = (const float*)d_in[12];
    const float* b4     = (const float*)d_in[13];

    const int N = N_NODES;

    auto align = [](size_t o) { return (o + 255) & ~(size_t)255; };
    char* base = (char*)d_ws;
    size_t off = 0;
    int*  tmp      = (int*)(base + off);  off = align(off + (size_t)ABLK * CH * 4);
    int*  starts_m = (int*)(base + off);  off = align(off + (size_t)NBUK * ABLK * 4);
    int*  counts_m = (int*)(base + off);  off = align(off + (size_t)NBUK * ABLK * 4);
    int2* row_info = (int2*)(base + off); off = align(off + (size_t)N * 8);
    ushort_t* csr  = (ushort_t*)(base + off); off = align(off + (size_t)NBUK * PAD2 * 2 + 256);
    uint4* pw      = (uint4*)(base + off);    off = align(off + (size_t)3 * 1024 * 16);
    ushort_t* tbA  = (ushort_t*)(base + off); off = align(off + (size_t)(N + 1) * 64 * 2);
    ushort_t* tbB  = (ushort_t*)(base + off); off = align(off + (size_t)(N + 1) * 64 * 2);
    float* uA = (float*)(base + off); off = align(off + (size_t)N * 64 * 4);
    float* uB = (float*)(base + off); off = align(off + (size_t)N * 64 * 4);

    float* out1 = (float*)d_out;
    float* out2 = (float*)d_out + (size_t)N * 64;

    // 1) block-local bucket sort + W packing
    build_a_kernel<<<ABLK + 3, 512, 0, stream>>>(ei, tmp, starts_m, counts_m,
                                                 Wnbr2, Wself2, Wnbr3, Wself3, Wnbr4, Wself4, pw);
    // 2) per-bucket counting sort (4-aligned) || gemm1 from x -> t1(tbA), u1(uA)
    build_b_kernel<<<NBUK + 1024, 512, 0, stream>>>(tmp, starts_m, counts_m, row_info, csr,
                                                    x, Wrel1, Wroot1, b1, tbA, uA);
    // 3) F1: agg1(mean) + gemm2 -> t2(tbB), u2(uB)
    fused_kernel<<<FBLK, 256, 0, stream>>>(tbA, uA, row_info, csr, pw,        b2, tbB, uB, nullptr, 1);
    // 4) F2: agg2 -> out1, + gemm3 -> t3(tbA), u3(uA)
    fused_kernel<<<FBLK, 256, 0, stream>>>(tbB, uB, row_info, csr, pw + 1024, b3, tbA, uA, out1, 0);
    // 5) F3: agg3 + gemm4 -> t4(tbB), u4(uB)
    fused_kernel<<<FBLK, 256, 0, stream>>>(tbA, uA, row_info, csr, pw + 2048, b4, tbB, uB, nullptr, 0);
    // 6) F4: agg4 -> out2
    agg_kernel<<<(N + 3) / 4, 256, 0, stream>>>(tbB, uB, row_info, csr, out2, 0);
}